// Round 5
// baseline (441.736 us; speedup 1.0000x reference)
//
#include <hip/hip_runtime.h>

typedef _Float16 half8 __attribute__((ext_vector_type(8)));
typedef float    f32x4 __attribute__((ext_vector_type(4)));

#define LDS_BYTES (131072 + 512)   // S_gates 64K | S_cx 64K | t double-buffer

__device__ __forceinline__ float rcpf(float x) { return __builtin_amdgcn_rcpf(x); }
__device__ __forceinline__ float sigf(float x)  { return rcpf(1.0f + __expf(-x)); }
__device__ __forceinline__ float tanhf_(float x){ return 1.0f - 2.0f * rcpf(1.0f + __expf(2.0f * x)); }

// ---------------- prepack: fp32 weights -> f16 MFMA-fragment granules in ws ----------------
// Gate granules (1 MiB @ wp+0): id = ((hb*16 + s)*4 + g), 1 KiB each  [hb-major so one
//   wave's whole K-stream is a contiguous 64 KiB run; 4 gates of a k-slice are imm 0..3072].
//   Lane l byte l*16, elem e = W[g*256 + hb*16 + (l&15)][s*32 + (l>>4)*8 + e]; K=512=[Wih|Whh].
// Decomp granules (128 KiB @ wp+1MiB): id = (hb*8 + s), value = Wd[k][h] (f16 hi; lo
//   correction comes from splitting cx, reusing the SAME B fragment for both passes).
__global__ __launch_bounds__(512) void prepack_kernel(
    const float* __restrict__ wih, const float* __restrict__ whh,
    const float* __restrict__ wd, char* __restrict__ wp)
{
  int idx = blockIdx.x * 512 + threadIdx.x;
  if (idx < 65536) {                       // gates: 8 consecutive k per thread
    int n  = idx >> 6;                     // 0..1023 = g*256 + h
    int k8 = (idx & 63) << 3;              // 0..504
    const float* src = (k8 < 256) ? (wih + n * 256 + k8) : (whh + n * 256 + (k8 - 256));
    f32x4 v0 = *(const f32x4*)src;
    f32x4 v1 = *(const f32x4*)(src + 4);
    half8 hv;
#pragma unroll
    for (int e = 0; e < 4; ++e) { hv[e] = (_Float16)v0[e]; hv[e + 4] = (_Float16)v1[e]; }
    int g = n >> 8, h = n & 255;
    int gran = (((h >> 4) << 4) + (k8 >> 5)) * 4 + g;
    int lane = (h & 15) + (((k8 >> 3) & 3) << 4);
    *(half8*)(wp + (gran << 10) + (lane << 4)) = hv;
  } else {                                 // decomp: scalar (coalesced reads over h)
    int i2 = idx - 65536;
    int h = i2 & 255, k = i2 >> 8;
    float v = wd[k * 256 + h];
    int gran = ((h >> 4) << 3) + (k >> 5);
    int lane = (h & 15) + (((k >> 3) & 3) << 4);
    *(_Float16*)(wp + (1 << 20) + (gran << 10) + (lane << 4) + ((k & 7) << 1)) = (_Float16)v;
  }
}

// ---------------- fused TA-LSTM cell: persistent 2-phase pipeline ----------------
// 256 blocks (1/CU) x 1024 thr (16 waves); block owns 4 tiles of 64 rows x 256 h.
// LDS: S_gates[64K] = in|hx fragment-major granules [sec][m][s]; S_cx[64K] = hi|lo [m][s].
// Phase A(i): gates MFMA from S_gates(i)  || stage cx(i) (issued at s==8) -> S_cx. barrier.
// Phase B(i): decomp MFMA from S_cx(i)    || stage in+hx(i+1) (issued at s==2);
//             epilogue(i); write S_gates(i+1). barrier.
__global__ __launch_bounds__(1024, 4) void talstm_kernel(
    const float* __restrict__ inp, const float* __restrict__ tt,
    const float* __restrict__ hx,  const float* __restrict__ cx,
    const float* __restrict__ bih, const float* __restrict__ bhh,
    const float* __restrict__ bd,  const char* __restrict__ wp,
    float* __restrict__ out)
{
  extern __shared__ __align__(16) char smem[];
  float* tsh = (float*)(smem + 131072);    // 2 x 64 floats
  const int tid  = threadIdx.x;
  const int lane = tid & 63;
  const int w    = __builtin_amdgcn_readfirstlane(tid >> 6);   // wave id = h-block (0..15)
  const int l15  = lane & 15;
  const int kq8  = (lane >> 4) << 3;
  const int laneB = lane << 4;
  const int tile0 = blockIdx.x << 2;

  // per-thread epilogue constants
  const int h  = (w << 4) + l15;
  const float bi  = bih[h]       + bhh[h];
  const float bfg = bih[256 + h] + bhh[256 + h];
  const float bg  = bih[512 + h] + bhh[512 + h];
  const float bo  = bih[768 + h] + bhh[768 + h];
  const float bdv = bd[h];
  const int er   = (lane >> 4) << 2;
  const int hoff = ((w >> 1) << 10) + ((((w & 1) << 1) + (l15 >> 3)) << 8) + ((l15 & 7) << 1);

  const char* a0 = smem + laneB;           // S_gates
  const char* a1 = smem + 65536 + laneB;   // S_cx (hi; lo at +32768)
  const char* wgp  = wp + (w << 16) + laneB;              // gate run: s at +s*4096, g at +g*1024
  const char* wdp  = wp + (1 << 20) + (w << 13) + laneB;  // decomp run: s at +s*1024

  // ---- prologue: stage in+hx(tile0) + t(tile0) ----
  {
    const int rb0 = tile0 << 6;
#pragma unroll
    for (int gi = 0; gi < 4; ++gi) {
      int gid = (w << 2) + gi;             // 0..63: sec|m|s
      int sec = gid >> 5, m = (gid >> 3) & 3, ss = gid & 7;
      const float* p = (sec ? hx : inp) + (size_t)(rb0 + (m << 4) + l15) * 256 + (ss << 5) + kq8;
      f32x4 v0 = *(const f32x4*)p, v1 = *(const f32x4*)(p + 4);
      half8 hv;
#pragma unroll
      for (int e = 0; e < 4; ++e) { hv[e] = (_Float16)v0[e]; hv[e + 4] = (_Float16)v1[e]; }
      *(half8*)(smem + (gid << 10) + laneB) = hv;
    }
    if (tid < 64) tsh[tid] = tt[rb0 + tid];
  }
  __syncthreads();

#pragma unroll 1
  for (int it = 0; it < 4; ++it) {
    const int rbase = (tile0 + it) << 6;
    const bool more = (it < 3);

    // ================= PHASE A: gates + cx-stage =================
    f32x4 acc[4][4];
    const f32x4 fz = {0.f, 0.f, 0.f, 0.f};
#pragma unroll
    for (int g = 0; g < 4; ++g)
#pragma unroll
      for (int m = 0; m < 4; ++m) acc[g][m] = fz;

    half8 nb0 = *(const half8*)(wgp);
    half8 nb1 = *(const half8*)(wgp + 1024);
    half8 nb2 = *(const half8*)(wgp + 2048);
    half8 nb3 = *(const half8*)(wgp + 3072);
    f32x4 cv[2][2];
    const int cg = w << 1;                 // this wave's two cx granules

#pragma unroll
    for (int s = 0; s < 16; ++s) {
      half8 b0 = nb0, b1 = nb1, b2 = nb2, b3 = nb3;
      if (s < 15) {
        const char* p = wgp + ((s + 1) << 12);
        nb0 = *(const half8*)(p);
        nb1 = *(const half8*)(p + 1024);
        nb2 = *(const half8*)(p + 2048);
        nb3 = *(const half8*)(p + 3072);
      }
      if (s == 8) {                        // issue cx stage loads (HBM latency hides under s=9..15)
#pragma unroll
        for (int gi = 0; gi < 2; ++gi) {
          int g2 = cg + gi, m = g2 >> 3, ss = g2 & 7;
          const float* p = cx + (size_t)(rbase + (m << 4) + l15) * 256 + (ss << 5) + kq8;
          cv[gi][0] = *(const f32x4*)p;
          cv[gi][1] = *(const f32x4*)(p + 4);
        }
      }
      const int so = ((s >> 3) << 15) + ((s & 7) << 10);
#pragma unroll
      for (int m = 0; m < 4; ++m) {
        half8 a = *(const half8*)(a0 + so + (m << 13));
        acc[0][m] = __builtin_amdgcn_mfma_f32_16x16x32_f16(a, b0, acc[0][m], 0, 0, 0);
        acc[1][m] = __builtin_amdgcn_mfma_f32_16x16x32_f16(a, b1, acc[1][m], 0, 0, 0);
        acc[2][m] = __builtin_amdgcn_mfma_f32_16x16x32_f16(a, b2, acc[2][m], 0, 0, 0);
        acc[3][m] = __builtin_amdgcn_mfma_f32_16x16x32_f16(a, b3, acc[3][m], 0, 0, 0);
      }
    }
    // convert + write cx hi/lo granules
#pragma unroll
    for (int gi = 0; gi < 2; ++gi) {
      half8 hv, lv;
#pragma unroll
      for (int e = 0; e < 4; ++e) {
        hv[e]     = (_Float16)cv[gi][0][e]; lv[e]     = (_Float16)(cv[gi][0][e] - (float)hv[e]);
        hv[e + 4] = (_Float16)cv[gi][1][e]; lv[e + 4] = (_Float16)(cv[gi][1][e] - (float)hv[e + 4]);
      }
      *(half8*)(smem + 65536 + ((cg + gi) << 10) + laneB) = hv;
      *(half8*)(smem + 98304 + ((cg + gi) << 10) + laneB) = lv;
    }
    __syncthreads();

    // ================= PHASE B: decomp + epilogue + next in/hx-stage =================
    f32x4 accd[4];
#pragma unroll
    for (int m = 0; m < 4; ++m) accd[m] = fz;

    half8 nbd = *(const half8*)(wdp);
    f32x4 sv[4][2];
    const int nrbase = rbase + 64;

#pragma unroll
    for (int s = 0; s < 8; ++s) {
      half8 b = nbd;
      if (s < 7) nbd = *(const half8*)(wdp + ((s + 1) << 10));
      if (s == 2 && more) {                // issue next-tile in+hx stage loads
#pragma unroll
        for (int gi = 0; gi < 4; ++gi) {
          int gid = (w << 2) + gi;
          int sec = gid >> 5, m = (gid >> 3) & 3, ss = gid & 7;
          const float* p = (sec ? hx : inp) + (size_t)(nrbase + (m << 4) + l15) * 256 + (ss << 5) + kq8;
          sv[gi][0] = *(const f32x4*)p;
          sv[gi][1] = *(const f32x4*)(p + 4);
        }
      }
#pragma unroll
      for (int m = 0; m < 4; ++m) {
        half8 ah = *(const half8*)(a1 + (m << 13) + (s << 10));
        half8 al = *(const half8*)(a1 + 32768 + (m << 13) + (s << 10));
        accd[m] = __builtin_amdgcn_mfma_f32_16x16x32_f16(ah, b, accd[m], 0, 0, 0);
        accd[m] = __builtin_amdgcn_mfma_f32_16x16x32_f16(al, b, accd[m], 0, 0, 0);
      }
    }

    // stage-write next in+hx granules (before epilogue so ds_writes overlap store latency)
    if (more) {
#pragma unroll
      for (int gi = 0; gi < 4; ++gi) {
        half8 hv;
#pragma unroll
        for (int e = 0; e < 4; ++e) { hv[e] = (_Float16)sv[gi][0][e]; hv[e + 4] = (_Float16)sv[gi][1][e]; }
        *(half8*)(smem + (((w << 2) + gi) << 10) + laneB) = hv;
      }
      if (tid < 64) tsh[(((it + 1) & 1) << 6) + tid] = tt[nrbase + tid];
    }

    // epilogue
    const float* tcur = tsh + ((it & 1) << 6);
#pragma unroll
    for (int m = 0; m < 4; ++m) {
      float* po = out + (size_t)(rbase + (m << 4) + er) * 256 + h;
      const char* chp = smem + 65536 + (m << 13) + (er << 4) + hoff;
#pragma unroll
      for (int e = 0; e < 4; ++e) {
        const float tv = tcur[(m << 4) + er + e];
        const float T  = (tv != 0.0f) ? rcpf(tv) : 0.0f;
        const float cxv = (float)*(const _Float16*)(chp + (e << 4))
                        + (float)*(const _Float16*)(chp + 32768 + (e << 4));
        const float gi  = sigf  (acc[0][m][e] + bi);
        const float gf  = sigf  (acc[1][m][e] + bfg);
        const float gg  = tanhf_(acc[2][m][e] + bg);
        const float go  = sigf  (acc[3][m][e] + bo);
        const float cst = tanhf_(accd[m][e] + bdv);
        const float cxa = cxv - cst + T * cst;
        const float cy  = gf * cxa + gi * gg;
        const float hy  = go * tanhf_(cy);
        po[(size_t)e * 256]               = hy;
        po[16777216ull + (size_t)e * 256] = cy;
      }
    }
    __syncthreads();
  }
}

extern "C" void kernel_launch(void* const* d_in, const int* in_sizes, int n_in,
                              void* d_out, int out_size, void* d_ws, size_t ws_size,
                              hipStream_t stream) {
  const float* inp = (const float*)d_in[0];
  const float* t   = (const float*)d_in[1];
  const float* hx  = (const float*)d_in[2];
  const float* cx  = (const float*)d_in[3];
  const float* wih = (const float*)d_in[4];
  const float* whh = (const float*)d_in[5];
  const float* bih = (const float*)d_in[6];
  const float* bhh = (const float*)d_in[7];
  const float* wd  = (const float*)d_in[8];
  const float* bd  = (const float*)d_in[9];
  float* out = (float*)d_out;
  char* wp = (char*)d_ws;   // 1.125 MiB: 1 MiB gate granules + 128 KiB decomp granules

  prepack_kernel<<<256, 512, 0, stream>>>(wih, whh, wd, wp);

  hipFuncSetAttribute((const void*)talstm_kernel,
                      hipFuncAttributeMaxDynamicSharedMemorySize, LDS_BYTES);
  talstm_kernel<<<256, 1024, LDS_BYTES, stream>>>(inp, t, hx, cx, bih, bhh, bd, wp, out);
}